// Round 4
// baseline (970.132 us; speedup 1.0000x reference)
//
#include <hip/hip_runtime.h>

// Soft-DTW (gamma=1), 64 batches of (1024 x 1024, 2-D points).
// Log2-domain: T = R * log2(e).
//   T_d[i] = cost2(i,d-i) + m - log2( exp2(m-T_{d-2}[i-1])
//                                   + exp2(m-T_{d-1}[i-1])
//                                   + exp2(m-T_{d-1}[i]) ),  m = min3
// cost2 = squared distance with coords pre-scaled by sqrt(log2 e).
// Mathematically identical to the reference softmin recurrence (verified
// R-domain variant passed in R1 with absmax 0.0).
//
// Safety by construction (replaces R2/R3's buggy exp-domain scaling):
//  - no scale factors / ldexp / per-lane k at all;
//  - boundary "inf" = finite sentinel: contour LDS padded with coord 1e15
//    -> out-of-range cells get cost ~1.4e30 and are ignored by softmin
//    (exp2(-1e30) = 0). Max accumulated sentinel: 2047*2.9e30 ~ 6e33 < fp32
//    max -> never inf. Min-term of softmin always contributes exp2(0)=1 ->
//    s in [1,3] -> log2(s) never sees 0 -> never NaN. No index guards.
//
// Layout: 1 block/batch, 256 threads = 4 waves, lane owns 4 consecutive
// rows. Neighbor (row 4t-1) lines flow via __shfl_up within a wave and via
// tiny double-buffered LDS slots across the 3 wave boundaries; one
// __syncthreads per diagonal (write slot[d&1] -> barrier -> read slot[d&1]
// next step; slot reused only two steps later -> race-free).
// Contour in LDS, swizzle w(j)=j+(j>>3) (stride-4-lane reads ~2-way = free),
// 4-deep register window, loop unrolled by 4 so window indices are static.

#define N 1024
#define C 4
#define T 256
#define NDIAG (2*N - 1)     // 2047
#define JOFF 1021           // j in [-1021, 2047] -> idx in [0, 3068]
#define LSZ 3456            // > swz(3068) = 3451

__device__ __forceinline__ int swz(int j) { return j + (j >> 3); }

__global__ __launch_bounds__(T) void dtw_kernel(
    const float2* __restrict__ snake,
    const float2* __restrict__ contour,
    float* __restrict__ out)
{
    const int b    = blockIdx.x;
    const int t    = threadIdx.x;
    const int lane = t & 63;
    const int w    = t >> 6;

    __shared__ float cxs[LSZ];
    __shared__ float cys[LSZ];
    __shared__ float sR1[4][2];   // T_{d-1}[wave-boundary row]
    __shared__ float sR2[4][2];   // T_{d-2}[wave-boundary row]

    const float SQL = 1.2011224087864498f; // sqrt(log2 e)
    const float BIG = 1.0e30f;             // boundary sentinel (finite!)
    const float PAD = 1.0e15f;             // pad coordinate -> cost ~1.4e30

    // Pass 1: pad every LDS slot (including swizzle gaps).
    for (int i = t; i < LSZ; i += T) { cxs[i] = PAD; cys[i] = PAD; }
    __syncthreads();

    const float2* sg = snake   + b * N;
    const float2* cg = contour + b * N;

    // Pass 2: real contour (scaled), snake points to registers.
    float spx[C], spy[C];
#pragma unroll
    for (int q = 0; q < C; ++q) {
        float2 p  = sg[C*t + q];
        spx[q] = p.x * SQL; spy[q] = p.y * SQL;
        float2 pc = cg[C*t + q];
        int a = swz(C*t + q + JOFF);
        cxs[a] = pc.x * SQL;
        cys[a] = pc.y * SQL;
    }
    if (t < 4) {
        sR1[t][0] = sR1[t][1] = BIG;
        sR2[t][0] = sR2[t][1] = BIG;
    }

    float A_[C], B_[C];   // role-swapping lines (T_{d-1} / T_{d-2})
#pragma unroll
    for (int q = 0; q < C; ++q) { A_[q] = BIG; B_[q] = BIG; }

    __syncthreads();

    if (t == 0) {
        // Diagonals 0,1 from the reference init (all in log2 units):
        float dx, dy;
        dx = spx[0] - cxs[swz(JOFF + 0)]; dy = spy[0] - cys[swz(JOFF + 0)];
        float c00 = fmaf(dx, dx, dy * dy);
        dx = spx[0] - cxs[swz(JOFF + 1)]; dy = spy[0] - cys[swz(JOFF + 1)];
        float c01 = fmaf(dx, dx, dy * dy);
        dx = spx[1] - cxs[swz(JOFF + 0)]; dy = spy[1] - cys[swz(JOFF + 0)];
        float c10 = fmaf(dx, dx, dy * dy);
        B_[0] = c00;        // T_0[0]
        A_[0] = c01 + c00;  // T_1[0]
        A_[1] = c10 + c00;  // T_1[1]
    }

    // Contour register window: slot dd&3 holds c[dd - 4t].
    float cwx[4], cwy[4];
#pragma unroll
    for (int dd = -1; dd <= 2; ++dd) {
        int a = swz(dd - C*t + JOFF);
        cwx[dd & 3] = cxs[a];
        cwy[dd & 3] = cys[a];
    }

#define STEP(DV, P, Q, WI, PR) do {                                          \
    float nR1 = __shfl_up(P[3], 1);   /* T_{d-1}[4t-1] */                    \
    float nR2 = __shfl_up(Q[3], 1);   /* T_{d-2}[4t-1] */                    \
    if (lane == 0) {                                                         \
        if (w > 0) { nR1 = sR1[w-1][1-(PR)]; nR2 = sR2[w-1][1-(PR)]; }       \
        else       { nR1 = BIG; nR2 = BIG; }                                 \
    }                                                                        \
    float Nv[C];                                                             \
    _Pragma("unroll")                                                        \
    for (int q = 0; q < C; ++q) {                                            \
        float dx   = spx[q] - cwx[((WI) - q) & 3];                           \
        float dy   = spy[q] - cwy[((WI) - q) & 3];                           \
        float cost = fmaf(dx, dx, dy * dy);                                  \
        float a_ = P[q];                    /* T_{d-1}[i]   (left) */        \
        float b_ = (q == 0) ? nR1 : P[q-1]; /* T_{d-1}[i-1] (up)   */        \
        float c_ = (q == 0) ? nR2 : Q[q-1]; /* T_{d-2}[i-1] (diag) */        \
        float m  = fminf(fminf(a_, b_), c_);                                 \
        float s  = __builtin_exp2f(m - a_) + __builtin_exp2f(m - b_)         \
                 + __builtin_exp2f(m - c_);                                  \
        Nv[q] = cost + m - __builtin_log2f(s);                               \
    }                                                                        \
    { /* prefetch next diagonal's contour point (read-only LDS) */           \
        int a = swz((DV) + 1 - C*t + JOFF);                                  \
        cwx[((WI) + 1) & 3] = cxs[a];                                        \
        cwy[((WI) + 1) & 3] = cys[a];                                        \
    }                                                                        \
    _Pragma("unroll")                                                        \
    for (int q = 0; q < C; ++q) { Q[q] = Nv[q]; }                            \
    if (lane == 63 && w < 3) { sR1[w][PR] = Nv[3]; sR2[w][PR] = P[3]; }      \
    __syncthreads();                                                         \
} while (0)

    // d0 = 2, 6, ..., 2042; WI = d&3, PR = d&1 (compile-time per slot).
    for (int d0 = 2; d0 < NDIAG - 4; d0 += 4) {
        STEP(d0 + 0, A_, B_, 2, 0);
        STEP(d0 + 1, B_, A_, 3, 1);
        STEP(d0 + 2, A_, B_, 0, 0);
        STEP(d0 + 3, B_, A_, 1, 1);
    }
    STEP(2046, A_, B_, 2, 0);   // final diagonal -> B_[3] of thread 255

#undef STEP

    if (t == T - 1) {
        // T -> R: R = T * ln2; mean over 64 batches.
        float R = B_[3] * 0.6931471805599453f;
        atomicAdd(out, R * (1.0f / 64.0f));
    }
}

extern "C" void kernel_launch(void* const* d_in, const int* in_sizes, int n_in,
                              void* d_out, int out_size, void* d_ws, size_t ws_size,
                              hipStream_t stream) {
    const float2* snake   = (const float2*)d_in[0];
    const float2* contour = (const float2*)d_in[1];
    float* out = (float*)d_out;
    hipMemsetAsync(out, 0, sizeof(float), stream);
    dtw_kernel<<<64, T, 0, stream>>>(snake, contour, out);
}

// Round 5
// 718.159 us; speedup vs baseline: 1.3509x; 1.3509x over previous
//
#include <hip/hip_runtime.h>

// Soft-DTW (gamma=1), 64 batches of (1024 x 1024, 2-D points).
// Log2-domain (same verified numerics as R4, absmax 0.0):
//   T_d[i] = cost2 + m - log2(1 + exp2(m-mid) + exp2(m-hi))
// where {m,mid,hi} = sort3(left, up, diag) -- one softmin term is exp2(0)=1
// exactly, so only 2 exp2 + 1 log2 per cell (trans pipe was the widest).
// Boundary "inf" = finite sentinel: contour LDS padded with coord 1e15 ->
// OOB cells cost ~2.9e30, max accumulation 2047*2.9e30 ~ 6e33 < fp32 max ->
// never inf; softmin's min term contributes 1 -> log2 arg in [1,3] -> no NaN.
//
// NEW vs R4: barrier-free decoupled wave pipeline. Inter-wave deps are
// one-directional (wave w consumes only wave w-1's boundary row), so:
//  - wave w lane63 writes its boundary value per diagonal into a
//    full-history LDS buffer hist[w][d] (2048 entries -> no wrap, no
//    backpressure), and publishes prog[w]=d every 4 diagonals;
//  - wave w+1 lane0 spin-checks prog once per 4-step iteration (amortized)
//    and prefetches hist[w][d] one step ahead.
// LDS ops from one wave complete in order -> flag-after-data is safe;
// all 8 waves of the block are CU-resident -> spin cannot deadlock.
// 8 waves x 2 rows/lane: 2 waves/SIMD hide each other's trans/LDS latency.
// Per step per lane: 1 shfl_up + 2-cell softmin + 1 contour LDS read
// (+ divergent hist write/read on the 7 wave boundaries). No __syncthreads
// in the main loop at all.

#define N     1024
#define W     8
#define TPB   (W * 64)        // 512
#define NDIAG (2 * N - 1)     // 2047
#define JOFF  1021            // j in [-1021, 2047] -> idx in [0, 3068]
#define LSZ   3456            // > swz(3068) = 3451
#define HIST  2048

__device__ __forceinline__ int swz(int j) { return j + (j >> 3); }

__global__ __launch_bounds__(TPB) void dtw_kernel(
    const float2* __restrict__ snake,
    const float2* __restrict__ contour,
    float* __restrict__ out)
{
    const int b    = blockIdx.x;
    const int t    = threadIdx.x;
    const int lane = t & 63;
    const int w    = t >> 6;
    const int i0   = 2 * t;          // this lane owns rows i0, i0+1

    __shared__ float cxs[LSZ];
    __shared__ float cys[LSZ];
    __shared__ float hist[W - 1][HIST]; // hist[w][d] = T_d[128(w+1)-1]
    __shared__ int   prog[W];

    const float SQL = 1.2011224087864498f; // sqrt(log2 e)
    const float BIG = 1.0e30f;             // boundary sentinel (finite)
    const float PAD = 1.0e15f;             // pad coord -> cost ~2.9e30

    // ---- setup (2 barriers total; none in the main loop) ----
    for (int i = t; i < LSZ; i += TPB) { cxs[i] = PAD; cys[i] = PAD; }
    if (t < W) prog[t] = 1;
    if (t < 2 * (W - 1)) hist[t >> 1][t & 1] = BIG;
    __syncthreads();

    const float2* sg = snake   + b * N;
    const float2* cg = contour + b * N;

    {
        float2 p0 = cg[i0], p1 = cg[i0 + 1];
        cxs[swz(i0 + JOFF)]     = p0.x * SQL;
        cys[swz(i0 + JOFF)]     = p0.y * SQL;
        cxs[swz(i0 + 1 + JOFF)] = p1.x * SQL;
        cys[swz(i0 + 1 + JOFF)] = p1.y * SQL;
    }
    float2 sa = sg[i0], sb = sg[i0 + 1];
    const float spx0 = sa.x * SQL, spy0 = sa.y * SQL;
    const float spx1 = sb.x * SQL, spy1 = sb.y * SQL;
    __syncthreads();

    // DP state: P* = T_{d-1} rows (i0, i0+1); Q0 = T_{d-2} row i0;
    // nb2 = T_{d-2}[i0-1]; h0 = prefetched hist value (lane 0 of wave>0).
    float P0 = BIG, P1 = BIG, Q0 = BIG, nb2 = BIG, h0 = BIG;
    if (t == 0) {
        // Diagonals 0,1 from the reference init (log2 units):
        float dx, dy;
        dx = spx0 - cxs[swz(JOFF + 0)]; dy = spy0 - cys[swz(JOFF + 0)];
        float c00 = fmaf(dx, dx, dy * dy);
        dx = spx0 - cxs[swz(JOFF + 1)]; dy = spy0 - cys[swz(JOFF + 1)];
        float c01 = fmaf(dx, dx, dy * dy);
        dx = spx1 - cxs[swz(JOFF + 0)]; dy = spy1 - cys[swz(JOFF + 0)];
        float c10 = fmaf(dx, dx, dy * dy);
        Q0 = c00;        // T_0[0]
        P0 = c01 + c00;  // T_1[0]
        P1 = c10 + c00;  // T_1[1]
    }

    // Rolling contour window: (cx0,cy0)=c[d-i0], (cx1,cy1)=c[d-i0-1].
    float cx0 = cxs[swz(2 - i0 + JOFF)], cy0 = cys[swz(2 - i0 + JOFF)];
    float cx1 = cxs[swz(1 - i0 + JOFF)], cy1 = cys[swz(1 - i0 + JOFF)];

    int cap = 1;  // cached upstream progress (lane 0 of waves > 0)

#define STEP(D) do {                                                         \
    float sh  = __shfl_up(P1, 1);                                            \
    float nb1 = (lane == 0) ? h0 : sh;      /* T_{d-1}[i0-1] */              \
    /* cell 0: row i0, col D-i0 */                                           \
    float dx0 = spx0 - cx0, dy0 = spy0 - cy0;                                \
    float cost0 = fmaf(dx0, dx0, dy0 * dy0);                                 \
    float m0  = fminf(fminf(P0, nb1), nb2);                                  \
    float md0 = __builtin_amdgcn_fmed3f(P0, nb1, nb2);                       \
    float hi0 = fmaxf(fmaxf(P0, nb1), nb2);                                  \
    float s0_ = 1.0f + __builtin_exp2f(m0 - md0) + __builtin_exp2f(m0 - hi0);\
    float Nv0 = cost0 + m0 - __builtin_log2f(s0_);                           \
    /* cell 1: row i0+1, col D-i0-1 */                                       \
    float dx1 = spx1 - cx1, dy1 = spy1 - cy1;                                \
    float cost1 = fmaf(dx1, dx1, dy1 * dy1);                                 \
    float m1  = fminf(fminf(P1, P0), Q0);                                    \
    float md1 = __builtin_amdgcn_fmed3f(P1, P0, Q0);                         \
    float hi1 = fmaxf(fmaxf(P1, P0), Q0);                                    \
    float s1_ = 1.0f + __builtin_exp2f(m1 - md1) + __builtin_exp2f(m1 - hi1);\
    float Nv1 = cost1 + m1 - __builtin_log2f(s1_);                           \
    /* publish boundary row; prefetch upstream boundary for step D+1 */      \
    if (lane == 63 && w < W - 1) ((volatile float*)hist[w])[D] = Nv1;        \
    if (lane == 0 && w > 0)      h0 = ((volatile float*)hist[w - 1])[D];     \
    /* commit + contour shift/prefetch c[D+1-i0] */                          \
    nb2 = nb1; Q0 = P0; P0 = Nv0; P1 = Nv1;                                  \
    cx1 = cx0; cy1 = cy0;                                                    \
    { int a_ = swz((D) + 1 - i0 + JOFF); cx0 = cxs[a_]; cy0 = cys[a_]; }     \
} while (0)

    // d = 2 .. 2045 in iterations of 4; then the final diagonal 2046.
    for (int d0 = 2; d0 <= 2042; d0 += 4) {
        if (w > 0 && lane == 0) {
            while (cap < d0 + 3) {              // need hist entries <= d0+3
                cap = ((volatile int*)prog)[w - 1];
                if (cap < d0 + 3) __builtin_amdgcn_s_sleep(2);
            }
        }
        STEP(d0); STEP(d0 + 1); STEP(d0 + 2); STEP(d0 + 3);
        if (lane == 63 && w < W - 1) ((volatile int*)prog)[w] = d0 + 3;
    }
    STEP(2046);   // result in P1 of thread TPB-1 (row 1023, col 1023)

#undef STEP

    if (t == TPB - 1) {
        float R = P1 * 0.6931471805599453f;   // log2 -> natural units
        atomicAdd(out, R * (1.0f / 64.0f));
    }
}

extern "C" void kernel_launch(void* const* d_in, const int* in_sizes, int n_in,
                              void* d_out, int out_size, void* d_ws, size_t ws_size,
                              hipStream_t stream) {
    const float2* snake   = (const float2*)d_in[0];
    const float2* contour = (const float2*)d_in[1];
    float* out = (float*)d_out;
    hipMemsetAsync(out, 0, sizeof(float), stream);
    dtw_kernel<<<64, TPB, 0, stream>>>(snake, contour, out);
}

// Round 6
// 613.595 us; speedup vs baseline: 1.5811x; 1.1704x over previous
//
#include <hip/hip_runtime.h>

// Soft-DTW (gamma=1), 64 batches of (1024 x 1024, 2-D points).
// Log2-domain (verified numerics, R4/R5 absmax 0.0):
//   T_d[i] = cost2 + m - log2(1 + exp2(m-mid) + exp2(m-hi)),
//   {m,mid,hi} = sort3(left, up, diag); coords pre-scaled by sqrt(log2 e).
// Boundary "inf" = finite sentinel: padded contour coord 1e15 -> OOB cost
// ~2.9e30; max accumulation 2047*2.9e30 ~ 6e33 < fp32 max -> never inf;
// softmin min-term contributes exp2(0)=1 -> log2 arg in [1,3] -> never NaN.
//
// R6 vs R5: the per-step DS-pipe serialization was the bottleneck (5 in-order
// LDS ops/step, volatile-forced lgkmcnt(0) drains -> ~785 cy/step at 19.6%
// VALUBusy). Now exactly ONE DS op per step (the ds_bpermute shfl):
//  - contour lives in a 5-point float2 register window; refilled 4 points
//    per 4-step group via two ds_read_b128 issued a full group ahead
//    (latency hidden); zero per-step contour reads or address math;
//  - wave-boundary handoff batched: producer lane63 accumulates 4 boundary
//    values in regs, one ds_write_b128 + one prog store per group; consumer
//    lane0 spin-checks prog then one ds_read_b128 per group; per-step use is
//    a static-index register select. In-order DS completion per wave makes
//    flag-after-data safe (same discipline R5 validated).
// 8 waves x 2 rows/lane, barrier-free decoupled pipeline, full-history hist
// buffer (no wraparound -> no backpressure), s_sleep spin (all waves
// resident -> no deadlock).

#define N     1024
#define W     8
#define TPB   (W * 64)      // 512
#define CPAD  1024          // cpts index = contour j + CPAD
#define CSZ   3104          // j in [-1022, 2056] -> idx in [2, 3080]
#define HIST  2048

__global__ __launch_bounds__(TPB) void dtw_kernel(
    const float2* __restrict__ snake,
    const float2* __restrict__ contour,
    float* __restrict__ out)
{
    const int b    = blockIdx.x;
    const int t    = threadIdx.x;
    const int lane = t & 63;
    const int w    = t >> 6;
    const int i0   = 2 * t;            // lane owns rows i0, i0+1

    __shared__ __align__(16) float2 cpts[CSZ];
    __shared__ __align__(16) float  hist[W - 1][HIST]; // hist[w][d-2] = T_d[128(w+1)-1]
    __shared__ int prog[W];

    const float SQL = 1.2011224087864498f; // sqrt(log2 e)
    const float BIG = 1.0e30f;             // boundary sentinel (finite)
    const float PAD = 1.0e15f;             // pad coord -> cost ~2.9e30

    // ---- setup (2 barriers total; none in the main loop) ----
    for (int i = t; i < CSZ; i += TPB) cpts[i] = make_float2(PAD, PAD);
    if (t < W) prog[t] = 1;
    __syncthreads();

    const float2* sg = snake   + b * N;
    const float2* cg = contour + b * N;

    {
        float2 a0 = cg[i0], a1 = cg[i0 + 1];
        cpts[CPAD + i0]     = make_float2(a0.x * SQL, a0.y * SQL);
        cpts[CPAD + i0 + 1] = make_float2(a1.x * SQL, a1.y * SQL);
    }
    float2 sa = sg[i0], sb = sg[i0 + 1];
    const float spx0 = sa.x * SQL, spy0 = sa.y * SQL;
    const float spx1 = sb.x * SQL, spy1 = sb.y * SQL;
    __syncthreads();

    // DP state: P0/P1 = T_{d-1}[i0]/[i0+1]; Q0 = T_{d-2}[i0];
    // nb2 = T_{d-2}[i0-1] (arrives via prev step's nb1).
    float P0 = BIG, P1 = BIG, Q0 = BIG, nb2 = BIG;
    if (t == 0) {
        float2 c0 = cpts[CPAD + 0], c1 = cpts[CPAD + 1];
        float dx, dy;
        dx = spx0 - c0.x; dy = spy0 - c0.y; float c00 = fmaf(dx, dx, dy * dy);
        dx = spx0 - c1.x; dy = spy0 - c1.y; float c01 = fmaf(dx, dx, dy * dy);
        dx = spx1 - c0.x; dy = spy1 - c0.y; float c10 = fmaf(dx, dx, dy * dy);
        Q0 = c00;        // T_0[0]
        P0 = c01 + c00;  // T_1[0]
        P1 = c10 + c00;  // T_1[1]
    }

    // Contour register window for group d0: pk = c[d0 - i0 - 4 + k], k=3..7.
    // Cell0 at step s uses k=4+s; cell1 uses k=3+s.
    float2 p3, p4, p5, p6, p7;
    {
        int base = CPAD - i0 - 2;   // = CPAD + (2 - i0 - 4)
        p3 = cpts[base + 3]; p4 = cpts[base + 4]; p5 = cpts[base + 5];
        p6 = cpts[base + 6]; p7 = cpts[base + 7];
    }

    float  hcarry = BIG;                        // hist value for diag d0-1
    float4 hb = make_float4(BIG, BIG, BIG, BIG);// hist diags d0..d0+3 (w>0)
    int    cap = 1;
    float  pr0 = 0.f, pr1 = 0.f, pr2 = 0.f, pr3 = 0.f;

#define STEP(HV, CA, CB, PRS) do {                                           \
    float sh  = __shfl_up(P1, 1);                                            \
    float nb1 = (lane == 0) ? (HV) : sh;        /* T_{d-1}[i0-1] */          \
    float dx0 = spx0 - CA.x, dy0 = spy0 - CA.y;                              \
    float cost0 = fmaf(dx0, dx0, dy0 * dy0);                                 \
    float m0  = fminf(fminf(P0, nb1), nb2);                                  \
    float md0 = __builtin_amdgcn_fmed3f(P0, nb1, nb2);                       \
    float hi0 = fmaxf(fmaxf(P0, nb1), nb2);                                  \
    float s0  = 1.0f + __builtin_exp2f(m0 - md0) + __builtin_exp2f(m0 - hi0);\
    float Nv0 = cost0 + m0 - __builtin_log2f(s0);                            \
    float dx1 = spx1 - CB.x, dy1 = spy1 - CB.y;                              \
    float cost1 = fmaf(dx1, dx1, dy1 * dy1);                                 \
    float m1  = fminf(fminf(P1, P0), Q0);                                    \
    float md1 = __builtin_amdgcn_fmed3f(P1, P0, Q0);                         \
    float hi1 = fmaxf(fmaxf(P1, P0), Q0);                                    \
    float s1  = 1.0f + __builtin_exp2f(m1 - md1) + __builtin_exp2f(m1 - hi1);\
    float Nv1 = cost1 + m1 - __builtin_log2f(s1);                            \
    PRS = Nv1;                                                               \
    nb2 = nb1; Q0 = P0; P0 = Nv0; P1 = Nv1;                                  \
} while (0)

    for (int d0 = 2; d0 <= 2042; d0 += 4) {
        if (w > 0 && lane == 0) {
            while (cap < d0 + 3) {
                cap = ((volatile int*)prog)[w - 1];
                if (cap < d0 + 3) __builtin_amdgcn_s_sleep(1);
            }
            __asm__ __volatile__("" ::: "memory");
            hb = *(const float4*)&hist[w - 1][d0 - 2]; // diags d0..d0+3
        }
        // Prefetch next group's 4 window points (consumed a group later).
        float4 na, nb_;
        {
            int idx0 = CPAD + d0 + 4 - i0;             // even -> 16B aligned
            na  = *(const float4*)&cpts[idx0];
            nb_ = *(const float4*)&cpts[idx0 + 2];
        }
        STEP(hcarry, p4, p3, pr0);   // diag d0
        STEP(hb.x,   p5, p4, pr1);   // diag d0+1
        STEP(hb.y,   p6, p5, pr2);   // diag d0+2
        STEP(hb.z,   p7, p6, pr3);   // diag d0+3
        if (lane == 63 && w < W - 1) {
            *(float4*)&hist[w][d0 - 2] = make_float4(pr0, pr1, pr2, pr3);
            __asm__ __volatile__("" ::: "memory");
            ((volatile int*)prog)[w] = d0 + 3;
        }
        hcarry = hb.w;               // diag d0+3 value, next group's s=0
        p3 = p7;
        p4 = make_float2(na.x,  na.y);  p5 = make_float2(na.z,  na.w);
        p6 = make_float2(nb_.x, nb_.y); p7 = make_float2(nb_.z, nb_.w);
    }
    // Final diagonal 2046 (hcarry = diag 2045 handoff, window rotated).
    { float dmy; STEP(hcarry, p4, p3, dmy); (void)dmy; }

#undef STEP

    if (t == TPB - 1) {
        float R = P1 * 0.6931471805599453f;   // log2 -> natural units
        atomicAdd(out, R * (1.0f / 64.0f));
    }
}

extern "C" void kernel_launch(void* const* d_in, const int* in_sizes, int n_in,
                              void* d_out, int out_size, void* d_ws, size_t ws_size,
                              hipStream_t stream) {
    const float2* snake   = (const float2*)d_in[0];
    const float2* contour = (const float2*)d_in[1];
    float* out = (float*)d_out;
    hipMemsetAsync(out, 0, sizeof(float), stream);
    dtw_kernel<<<64, TPB, 0, stream>>>(snake, contour, out);
}